// Round 4
// baseline (465.804 us; speedup 1.0000x reference)
//
#include <hip/hip_runtime.h>

// Problem constants (match reference)
#define H_  1024
#define W_  2048
#define HP  1026                 // H+2
#define WP  2050                 // W+2
#define GRID_F (HP*WP)           // 2,103,300 cells

// ws layout (float units)
// [0, 2*GRID_F)          interleaved float2 grid (feat, idx+1)   16.83 MB
// STATS_OFFF  +54        moment accumulators
// WIN_OFFF    +16*N      per-point window slots, 64B each        64 MB
#define STATS_OFFF 4206656                  // 64-aligned past 2*GRID_F=4,206,600
#define WIN_OFFF   4206720                  // byte offset 16,826,880 (64B-aligned)
#define ZERO_FLOATS (STATS_OFFF + 64)       // memset extent (winbuf needs no zeroing)

typedef float fvec4 __attribute__((ext_vector_type(4)));

// ---------------------------------------------------------------- scatter
// One scattered 8B store per point: (feature, point-index+1) interleaved.
__global__ __launch_bounds__(256) void scatter_k(
    const float* __restrict__ feats, const int2* __restrict__ coords,
    float2* __restrict__ gridi, int N)
{
    int i = blockIdx.x * 256 + threadIdx.x;
    if (i >= N) return;
    int2 c = coords[i];                       // c.x = y, c.y = x
    int cell = (c.x + 1) * WP + (c.y + 1);
    float2 v;
    v.x = feats[i];
    v.y = __int_as_float(i + 1);
    gridi[cell] = v;
}

// ---------------------------------------------------------------- stats + window scatter
// Dense row-order sweep. For each active cell: accumulate the 54 BN moment
// terms AND scatter the 9-float window into winbuf[idx] (full 64B line,
// aligned NT write -> no read-modify-write). Reads are sequential/L1-cached;
// the ONLY scattered stream in the whole pipeline is this 64 MB one.
__global__ __launch_bounds__(256) void stats_win_k(
    const float2* __restrict__ gridi, float* __restrict__ stats,
    fvec4* __restrict__ winbuf)
{
    const int off[9] = {-WP-1, -WP, -WP+1, -1, 0, 1, WP-1, WP, WP+1};
    float acc[54];
    #pragma unroll
    for (int j = 0; j < 54; ++j) acc[j] = 0.f;

    int stride = gridDim.x * blockDim.x;
    for (int c = blockIdx.x * blockDim.x + threadIdx.x; c < GRID_F; c += stride) {
        float2 g = gridi[c];
        int idx = __float_as_int(g.y);
        if (idx > 0) {                        // active center
            float p[9];
            #pragma unroll
            for (int k = 0; k < 9; ++k) p[k] = (k == 4) ? g.x : gridi[c + off[k]].x;
            #pragma unroll
            for (int k = 0; k < 9; ++k) acc[k] += p[k];
            int t = 9;
            #pragma unroll
            for (int k = 0; k < 9; ++k)
                #pragma unroll
                for (int l = k; l < 9; ++l) acc[t++] += p[k] * p[l];

            long b = (long)(idx - 1) * 4;     // fvec4 units; 64B per point
            fvec4 w0 = {p[0], p[1], p[2], p[3]};
            fvec4 w1 = {p[4], p[5], p[6], p[7]};
            fvec4 w2 = {p[8], 0.f, 0.f, 0.f};
            fvec4 w3 = {0.f, 0.f, 0.f, 0.f};
            __builtin_nontemporal_store(w0, &winbuf[b + 0]);
            __builtin_nontemporal_store(w1, &winbuf[b + 1]);
            __builtin_nontemporal_store(w2, &winbuf[b + 2]);
            __builtin_nontemporal_store(w3, &winbuf[b + 3]);   // full-line write
        }
    }

    __shared__ float part[4][54];
    int wave = threadIdx.x >> 6, lane = threadIdx.x & 63;
    #pragma unroll
    for (int j = 0; j < 54; ++j) {
        float v = acc[j];
        #pragma unroll
        for (int d = 32; d > 0; d >>= 1) v += __shfl_down(v, d, 64);
        if (lane == 0) part[wave][j] = v;
    }
    __syncthreads();
    if (threadIdx.x < 54) {
        float v = part[0][threadIdx.x] + part[1][threadIdx.x]
                + part[2][threadIdx.x] + part[3][threadIdx.x];
        atomicAdd(&stats[threadIdx.x], v);
    }
}

// ---------------------------------------------------------------- output
// Point-order pass, fully streaming: sequential reads of winbuf (64 MB),
// sequential 1KB/wave nontemporal stores of out (256 MB). 16 lanes/point,
// lanes q<9 load the window, shuffle-broadcast, 4 channels/lane from
// register-held weights. BN finalize fused in prologue. No coords read.
__global__ __launch_bounds__(256) void out_point_k(
    const float* __restrict__ winf, const float* __restrict__ w,
    const float* __restrict__ stats, const float* __restrict__ gamma,
    const float* __restrict__ beta, float* __restrict__ out, int N)
{
    __shared__ __align__(16) float sc_s[64];
    __shared__ __align__(16) float sh_s[64];

    int t = threadIdx.x;
    if (t < 64) {                              // fused finalize (per-block, cache-hit)
        int c = t;
        float invN = 1.0f / (float)N;
        float wc[9];
        #pragma unroll
        for (int k = 0; k < 9; ++k) wc[k] = w[k * 64 + c];
        float mean = 0.f;
        #pragma unroll
        for (int k = 0; k < 9; ++k) mean += stats[k] * invN * wc[k];
        float e2 = 0.f;
        int s = 9;
        #pragma unroll
        for (int k = 0; k < 9; ++k)
            #pragma unroll
            for (int l = k; l < 9; ++l) {
                float mm = stats[s++] * invN;
                e2 += (k == l ? 1.f : 2.f) * wc[k] * wc[l] * mm;
            }
        float var = e2 - mean * mean;
        float sc = gamma[c] * rsqrtf(var + 1e-5f);
        sc_s[c] = sc;
        sh_s[c] = beta[c] - mean * sc;
    }
    __syncthreads();

    int lane = t & 63;
    int q    = lane & 15;                      // channel quad / window slot 0..15
    int grp  = lane & 48;                      // group base lane (16-lane groups)

    // weights for this lane's 4 channels, held in registers (36 VGPRs)
    const fvec4* w4 = (const fvec4*)w;         // [9][16]
    fvec4 wq[9];
    #pragma unroll
    for (int k = 0; k < 9; ++k) wq[k] = w4[k * 16 + q];
    fvec4 sc4 = ((const fvec4*)sc_s)[q];
    fvec4 sh4 = ((const fvec4*)sh_s)[q];

    fvec4* out4 = (fvec4*)out;
    int gid = (blockIdx.x * 256 + t) >> 4;     // global 16-lane group id
    int G   = (gridDim.x * 256) >> 4;          // total groups

    for (int S = 0; S < N; S += 4 * G) {
        int pj[4];
        #pragma unroll
        for (int j = 0; j < 4; ++j) pj[j] = S + j * G + gid;

        // ---- load phase: 4 independent sequential window reads
        float v4[4];
        #pragma unroll
        for (int j = 0; j < 4; ++j) {
            v4[j] = 0.f;
            if (pj[j] < N && q < 9)
                v4[j] = winf[(long)pj[j] * 16 + q];   // wave reads 4 consecutive 64B lines
        }
        // ---- compute + store phase
        #pragma unroll
        for (int j = 0; j < 4; ++j) {
            if (pj[j] < N) {
                fvec4 acc = {0.f, 0.f, 0.f, 0.f};
                #pragma unroll
                for (int k = 0; k < 9; ++k) {
                    float pk = __shfl(v4[j], grp + k, 64);  // broadcast window val k
                    acc.x = fmaf(pk, wq[k].x, acc.x);
                    acc.y = fmaf(pk, wq[k].y, acc.y);
                    acc.z = fmaf(pk, wq[k].z, acc.z);
                    acc.w = fmaf(pk, wq[k].w, acc.w);
                }
                acc.x = fmaxf(fmaf(acc.x, sc4.x, sh4.x), 0.f);
                acc.y = fmaxf(fmaf(acc.y, sc4.y, sh4.y), 0.f);
                acc.z = fmaxf(fmaf(acc.z, sc4.z, sh4.z), 0.f);
                acc.w = fmaxf(fmaf(acc.w, sc4.w, sh4.w), 0.f);
                __builtin_nontemporal_store(acc, &out4[(long)pj[j] * 16 + q]);  // 1KB/wave seq
            }
        }
    }
}

// ---------------------------------------------------------------- launch
extern "C" void kernel_launch(void* const* d_in, const int* in_sizes, int n_in,
                              void* d_out, int out_size, void* d_ws, size_t ws_size,
                              hipStream_t stream)
{
    const float* feats  = (const float*)d_in[0];
    const float* weight = (const float*)d_in[1];   // [9][1][64]
    const float* gamma  = (const float*)d_in[2];
    const float* beta   = (const float*)d_in[3];
    const int2*  coords = (const int2*)d_in[4];    // [N][2] (y,x)
    float*       out    = (float*)d_out;
    int N = in_sizes[0];                           // C_IN == 1

    float*  ws     = (float*)d_ws;
    float2* gridi  = (float2*)ws;
    float*  stats  = ws + STATS_OFFF;
    fvec4*  winbuf = (fvec4*)(ws + WIN_OFFF);

    // zero interleaved grid + stats (ws is poisoned 0xAA); winbuf needs no zeroing:
    // every slot read by out_point_k (pt < N, q < 9) is fully written in stats_win_k.
    (void)hipMemsetAsync(d_ws, 0, (size_t)ZERO_FLOATS * sizeof(float), stream);

    scatter_k  <<<(N + 255) / 256, 256, 0, stream>>>(feats, coords, gridi, N);
    stats_win_k<<<2048, 256, 0, stream>>>(gridi, stats, winbuf);
    out_point_k<<<4096, 256, 0, stream>>>((const float*)winbuf, weight, stats,
                                          gamma, beta, out, N);
}

// Round 7
// 463.295 us; speedup vs baseline: 1.0054x; 1.0054x over previous
//
#include <hip/hip_runtime.h>

// Problem constants (match reference)
#define H_  1024
#define W_  2048
#define HP  1026                 // H+2
#define WP  2050                 // W+2
#define GRID_F (HP*WP)           // 2,103,300 cells = 8.41 MB fp32

// ws layout (float units)
#define MASK_OFFF  2103360                  // byte-mask (GRID_F bytes)
#define STATS_OFFF (MASK_OFFF + 525888)     // 54 moment accumulators
#define SCALE_OFFF (STATS_OFFF + 64)
#define SHIFT_OFFF (SCALE_OFFF + 64)
#define ZERO_FLOATS SCALE_OFFF              // memset extent (scale/shift fully overwritten)

typedef float fvec4 __attribute__((ext_vector_type(4)));

// ---------------------------------------------------------------- scatter
__global__ __launch_bounds__(256) void sc_kern(
    const float* __restrict__ feats, const int2* __restrict__ coords,
    float* __restrict__ grid, unsigned char* __restrict__ mask, int N)
{
    int i = blockIdx.x * 256 + threadIdx.x;
    if (i >= N) return;
    int2 c = coords[i];                       // c.x = y, c.y = x
    int cell = (c.x + 1) * WP + (c.y + 1);
    grid[cell] = feats[i];
    mask[cell] = 1;
}

// ---------------------------------------------------------------- stats
// Dense row-order pass: s[k] = sums (9), M[k][l] upper-tri moments (45).
__global__ __launch_bounds__(256) void st_kern(
    const float* __restrict__ grid, const unsigned char* __restrict__ mask,
    float* __restrict__ stats)
{
    const int off[9] = {-WP-1, -WP, -WP+1, -1, 0, 1, WP-1, WP, WP+1};
    float acc[54];
    #pragma unroll
    for (int j = 0; j < 54; ++j) acc[j] = 0.f;

    int stride = gridDim.x * blockDim.x;
    for (int c = blockIdx.x * blockDim.x + threadIdx.x; c < GRID_F; c += stride) {
        if (mask[c]) {                        // active center
            float p[9];
            #pragma unroll
            for (int k = 0; k < 9; ++k) p[k] = grid[c + off[k]];
            #pragma unroll
            for (int k = 0; k < 9; ++k) acc[k] += p[k];
            int t = 9;
            #pragma unroll
            for (int k = 0; k < 9; ++k)
                #pragma unroll
                for (int l = k; l < 9; ++l) acc[t++] += p[k] * p[l];
        }
    }

    __shared__ float part[4][54];
    int wave = threadIdx.x >> 6, lane = threadIdx.x & 63;
    #pragma unroll
    for (int j = 0; j < 54; ++j) {
        float v = acc[j];
        #pragma unroll
        for (int d = 32; d > 0; d >>= 1) v += __shfl_down(v, d, 64);
        if (lane == 0) part[wave][j] = v;
    }
    __syncthreads();
    if (threadIdx.x < 54) {
        float v = part[0][threadIdx.x] + part[1][threadIdx.x]
                + part[2][threadIdx.x] + part[3][threadIdx.x];
        atomicAdd(&stats[threadIdx.x], v);
    }
}

// ---------------------------------------------------------------- finalize
// Writes scale/shift to ws GLOBAL memory so the out kernel can read them as
// wave-uniform scalar loads (K$), not LDS.
__global__ __launch_bounds__(64) void fin_kern(
    const float* __restrict__ stats, const float* __restrict__ w,
    const float* __restrict__ gamma, const float* __restrict__ beta,
    float* __restrict__ scale, float* __restrict__ shift, int N)
{
    int c = threadIdx.x;                      // 0..63
    float invN = 1.0f / (float)N;
    float wc[9];
    #pragma unroll
    for (int k = 0; k < 9; ++k) wc[k] = w[k * 64 + c];
    float mean = 0.f;
    #pragma unroll
    for (int k = 0; k < 9; ++k) mean += stats[k] * invN * wc[k];
    float e2 = 0.f;
    int t = 9;
    #pragma unroll
    for (int k = 0; k < 9; ++k)
        #pragma unroll
        for (int l = k; l < 9; ++l) {
            float mm = stats[t++] * invN;
            e2 += (k == l ? 1.f : 2.f) * wc[k] * wc[l] * mm;
        }
    float var = e2 - mean * mean;
    float sc = gamma[c] * rsqrtf(var + 1e-5f);
    scale[c] = sc;
    shift[c] = beta[c] - mean * sc;
}

// ---------------------------------------------------------------- output
// One lane per point, zero DS ops: the 3x3 window sits in the lane's own
// registers (no cross-lane broadcast), weights/scale/shift are wave-uniform
// constant-indexed -> scalar K$ loads. k-outer / q-inner loop keeps only 64
// uniform weight floats live per step; acc[16] is statically indexed ->
// 64 VGPRs. Stores: 16x dwordx4 per point at 256B lane stride; one wave's
// 16 store instrs cover a contiguous 16KB region -> L2 merges full lines.
__global__ __launch_bounds__(256) void out_kern(
    const float* __restrict__ grid, const int2* __restrict__ coords,
    const float* __restrict__ w, const float* __restrict__ scale,
    const float* __restrict__ shift, float* __restrict__ out, int N)
{
    int i = blockIdx.x * 256 + threadIdx.x;
    if (i >= N) return;

    int2 c = coords[i];                       // c.x = y, c.y = x
    int cell = (c.x + 1) * WP + (c.y + 1);

    const int off[9] = {-WP-1, -WP, -WP+1, -1, 0, 1, WP-1, WP, WP+1};
    float p[9];
    #pragma unroll
    for (int k = 0; k < 9; ++k) p[k] = grid[cell + off[k]];   // 9 gathers, lane-local

    const fvec4* w4 = (const fvec4*)w;        // [9][16], uniform -> s_load
    fvec4 acc[16];
    #pragma unroll
    for (int q = 0; q < 16; ++q) acc[q] = (fvec4){0.f, 0.f, 0.f, 0.f};

    #pragma unroll
    for (int k = 0; k < 9; ++k) {
        float pk = p[k];
        #pragma unroll
        for (int q = 0; q < 16; ++q) {
            fvec4 wv = w4[k * 16 + q];
            acc[q].x = fmaf(pk, wv.x, acc[q].x);
            acc[q].y = fmaf(pk, wv.y, acc[q].y);
            acc[q].z = fmaf(pk, wv.z, acc[q].z);
            acc[q].w = fmaf(pk, wv.w, acc[q].w);
        }
    }

    const fvec4* sc4 = (const fvec4*)scale;   // uniform -> s_load
    const fvec4* sh4 = (const fvec4*)shift;
    fvec4* out4 = (fvec4*)out;
    long obase = (long)i * 16;
    #pragma unroll
    for (int q = 0; q < 16; ++q) {
        fvec4 s = sc4[q], h = sh4[q];
        fvec4 r;
        r.x = fmaxf(fmaf(acc[q].x, s.x, h.x), 0.f);
        r.y = fmaxf(fmaf(acc[q].y, s.y, h.y), 0.f);
        r.z = fmaxf(fmaf(acc[q].z, s.z, h.z), 0.f);
        r.w = fmaxf(fmaf(acc[q].w, s.w, h.w), 0.f);
        out4[obase + q] = r;                  // cached store; L2 merges sectors
    }
}

// ---------------------------------------------------------------- launch
extern "C" void kernel_launch(void* const* d_in, const int* in_sizes, int n_in,
                              void* d_out, int out_size, void* d_ws, size_t ws_size,
                              hipStream_t stream)
{
    const float* feats  = (const float*)d_in[0];
    const float* weight = (const float*)d_in[1];   // [9][1][64]
    const float* gamma  = (const float*)d_in[2];
    const float* beta   = (const float*)d_in[3];
    const int2*  coords = (const int2*)d_in[4];    // [N][2] (y,x)
    float*       out    = (float*)d_out;
    int N = in_sizes[0];                           // C_IN == 1

    float*         ws    = (float*)d_ws;
    float*         grid  = ws;
    unsigned char* mask  = (unsigned char*)(ws + MASK_OFFF);
    float*         stats = ws + STATS_OFFF;
    float*         scale = ws + SCALE_OFFF;
    float*         shift = ws + SHIFT_OFFF;

    // zero grid + mask + stats (ws is poisoned 0xAA)
    (void)hipMemsetAsync(d_ws, 0, (size_t)ZERO_FLOATS * sizeof(float), stream);

    sc_kern <<<(N + 255) / 256, 256, 0, stream>>>(feats, coords, grid, mask, N);
    st_kern <<<1024, 256, 0, stream>>>(grid, mask, stats);
    fin_kern<<<1, 64, 0, stream>>>(stats, weight, gamma, beta, scale, shift, N);
    out_kern<<<(N + 255) / 256, 256, 0, stream>>>(grid, coords, weight, scale, shift, out, N);
}

// Round 8
// 356.778 us; speedup vs baseline: 1.3056x; 1.2986x over previous
//
#include <hip/hip_runtime.h>

// Problem constants (match reference)
#define H_  1024
#define W_  2048
#define HP  1026                 // H+2
#define WP  2050                 // W+2
#define GRID_F (HP*WP)           // 2,103,300 cells = 8.41 MB fp32

// ws layout (floats)
#define IDX_OFF   2103360        // int grid, 64-aligned
#define STATS_OFF 4206720        // 54 moment accumulators
#define SCALE_OFF 4206784
#define SHIFT_OFF 4206848

typedef float fvec4 __attribute__((ext_vector_type(4)));

// ---------------------------------------------------------------- scatter
// Write feature value AND point-index(+1) into dense padded grids.
__global__ __launch_bounds__(256) void scatter_k(
    const float* __restrict__ feats, const int2* __restrict__ coords,
    float* __restrict__ grid, int* __restrict__ idxg, int N)
{
    int i = blockIdx.x * 256 + threadIdx.x;
    if (i >= N) return;
    int2 c = coords[i];                       // c.x = y, c.y = x
    int cell = (c.x + 1) * WP + (c.y + 1);
    grid[cell] = feats[i];
    idxg[cell] = i + 1;
}

// ---------------------------------------------------------------- stats
// Dense row-order pass: s[k] = sum over active cells of window val k (9),
// M[k][l] upper-tri second moments (45) -> 54 floats. All loads coalesced.
__global__ __launch_bounds__(256) void stats_dense_k(
    const float* __restrict__ grid, const int* __restrict__ idxg,
    float* __restrict__ stats)
{
    const int off[9] = {-WP-1, -WP, -WP+1, -1, 0, 1, WP-1, WP, WP+1};
    float acc[54];
    #pragma unroll
    for (int j = 0; j < 54; ++j) acc[j] = 0.f;

    int stride = gridDim.x * blockDim.x;
    for (int c = blockIdx.x * blockDim.x + threadIdx.x; c < GRID_F; c += stride) {
        if (idxg[c] > 0) {                    // active center
            float p[9];
            #pragma unroll
            for (int k = 0; k < 9; ++k) p[k] = grid[c + off[k]];
            #pragma unroll
            for (int k = 0; k < 9; ++k) acc[k] += p[k];
            int t = 9;
            #pragma unroll
            for (int k = 0; k < 9; ++k)
                #pragma unroll
                for (int l = k; l < 9; ++l) acc[t++] += p[k] * p[l];
        }
    }

    __shared__ float part[4][54];
    int wave = threadIdx.x >> 6, lane = threadIdx.x & 63;
    #pragma unroll
    for (int j = 0; j < 54; ++j) {
        float v = acc[j];
        #pragma unroll
        for (int d = 32; d > 0; d >>= 1) v += __shfl_down(v, d, 64);
        if (lane == 0) part[wave][j] = v;
    }
    __syncthreads();
    if (threadIdx.x < 54) {
        float v = part[0][threadIdx.x] + part[1][threadIdx.x]
                + part[2][threadIdx.x] + part[3][threadIdx.x];
        atomicAdd(&stats[threadIdx.x], v);
    }
}

// ---------------------------------------------------------------- finalize
__global__ __launch_bounds__(64) void finalize_k(
    const float* __restrict__ stats, const float* __restrict__ w,
    const float* __restrict__ gamma, const float* __restrict__ beta,
    float* __restrict__ scale, float* __restrict__ shift, int N)
{
    int c = threadIdx.x;                      // 0..63
    float invN = 1.0f / (float)N;
    float wc[9];
    #pragma unroll
    for (int k = 0; k < 9; ++k) wc[k] = w[k * 64 + c];
    float mean = 0.f;
    #pragma unroll
    for (int k = 0; k < 9; ++k) mean += stats[k] * invN * wc[k];
    float e2 = 0.f;
    int t = 9;
    #pragma unroll
    for (int k = 0; k < 9; ++k)
        #pragma unroll
        for (int l = k; l < 9; ++l) {
            float mm = stats[t++] * invN;
            e2 += (k == l ? 1.f : 2.f) * wc[k] * wc[l] * mm;
        }
    float var = e2 - mean * mean;
    float sc = gamma[c] * rsqrtf(var + 1e-5f);
    scale[c] = sc;
    shift[c] = beta[c] - mean * sc;
}

// ---------------------------------------------------------------- output
// Dense tile pass (round-0 structure, DS-thinned): 256 consecutive cells /
// block, compact active cells to LDS, stage windows in nb_s, compute 64
// channels per point (16 lanes x float4), NT-store 256B chunks.
// CHANGE vs round 0: weights + scale/shift are hoisted into REGISTERS
// (q = t&15 is loop-invariant), loaded from global (L1/K$-resident 2.3KB),
// eliminating 17 of 26 DS wave-instrs per u-step. LDS = nb_s + compaction
// only (~11 KB).
__global__ __launch_bounds__(256) void out_dense_k(
    const float* __restrict__ grid, const int* __restrict__ idxg,
    const float* __restrict__ w, const float* __restrict__ scale,
    const float* __restrict__ shift, float* __restrict__ out)
{
    __shared__ float nb_s[9][256];
    __shared__ int   cell_s[256];
    __shared__ int   oidx_s[256];
    __shared__ int   cnt;

    int t = threadIdx.x;
    if (t == 0) cnt = 0;

    // loop-invariant per-thread operands (q constant across u-steps)
    int q = t & 15;
    const fvec4* w4g = (const fvec4*)w;        // [9][16]
    fvec4 wq[9];
    #pragma unroll
    for (int k = 0; k < 9; ++k) wq[k] = w4g[k * 16 + q];
    fvec4 sc4 = ((const fvec4*)scale)[q];
    fvec4 sh4 = ((const fvec4*)shift)[q];

    __syncthreads();                           // cnt=0 visible

    int c = blockIdx.x * 256 + t;
    if (c < GRID_F) {
        int idx = idxg[c];
        if (idx > 0) {
            int p = atomicAdd(&cnt, 1);
            cell_s[p] = c;
            oidx_s[p] = idx - 1;
        }
    }
    __syncthreads();
    int M = cnt;
    if (M == 0) return;

    const int off[9] = {-WP-1, -WP, -WP+1, -1, 0, 1, WP-1, WP, WP+1};
    if (t < M) {
        int base = cell_s[t];
        #pragma unroll
        for (int k = 0; k < 9; ++k) nb_s[k][t] = grid[base + off[k]];
    }
    __syncthreads();

    fvec4* out4 = (fvec4*)out;
    for (int u = t; u < 16 * M; u += 256) {
        int pt = u >> 4;                       // compacted point
        fvec4 acc = {0.f, 0.f, 0.f, 0.f};
        #pragma unroll
        for (int k = 0; k < 9; ++k) {
            float pk = nb_s[k][pt];            // broadcast b32, 4 addrs/wave
            acc.x = fmaf(pk, wq[k].x, acc.x);
            acc.y = fmaf(pk, wq[k].y, acc.y);
            acc.z = fmaf(pk, wq[k].z, acc.z);
            acc.w = fmaf(pk, wq[k].w, acc.w);
        }
        acc.x = fmaxf(fmaf(acc.x, sc4.x, sh4.x), 0.f);
        acc.y = fmaxf(fmaf(acc.y, sc4.y, sh4.y), 0.f);
        acc.z = fmaxf(fmaf(acc.z, sc4.z, sh4.z), 0.f);
        acc.w = fmaxf(fmaf(acc.w, sc4.w, sh4.w), 0.f);
        __builtin_nontemporal_store(acc, &out4[(long)oidx_s[pt] * 16 + q]);
    }
}

// ---------------------------------------------------------------- launch
extern "C" void kernel_launch(void* const* d_in, const int* in_sizes, int n_in,
                              void* d_out, int out_size, void* d_ws, size_t ws_size,
                              hipStream_t stream)
{
    const float* feats  = (const float*)d_in[0];
    const float* weight = (const float*)d_in[1];   // [9][1][64]
    const float* gamma  = (const float*)d_in[2];
    const float* beta   = (const float*)d_in[3];
    const int2*  coords = (const int2*)d_in[4];    // [N][2] (y,x)
    float*       out    = (float*)d_out;
    int N = in_sizes[0];                           // C_IN == 1

    float* ws    = (float*)d_ws;
    float* grid  = ws;
    int*   idxg  = (int*)(ws + IDX_OFF);
    float* stats = ws + STATS_OFF;
    float* scale = ws + SCALE_OFF;
    float* shift = ws + SHIFT_OFF;

    // zero grid + idx grid + stats accumulators (ws is poisoned 0xAA)
    (void)hipMemsetAsync(d_ws, 0, (size_t)(STATS_OFF + 64) * sizeof(float), stream);

    scatter_k    <<<(N + 255) / 256, 256, 0, stream>>>(feats, coords, grid, idxg, N);
    stats_dense_k<<<1024, 256, 0, stream>>>(grid, idxg, stats);
    finalize_k   <<<1, 64, 0, stream>>>(stats, weight, gamma, beta, scale, shift, N);
    out_dense_k  <<<(GRID_F + 255) / 256, 256, 0, stream>>>(grid, idxg, weight, scale, shift, out);
}